// Round 5
// baseline (2217.266 us; speedup 1.0000x reference)
//
#include <hip/hip_runtime.h>
#include <math.h>

typedef unsigned short u16;
typedef unsigned int u32;
typedef __attribute__((ext_vector_type(8))) short short8;
typedef __attribute__((ext_vector_type(4))) float floatx4;

// ---------------- problem constants ----------------
#define BB 64
#define NTOK 197
#define NPATCH 196
#define EMB 192
#define NH 3
#define HD 64
#define FEAT 256
#define MLPD 768
#define NCLS 1000
#define MTOT (BB*NTOK)      // 12608 = 197*64 exactly
#define MPAT (BB*NPATCH)    // 12544
#define BHT (BB*NH)         // 192

// ---------------- bf16 helpers ----------------
__device__ __forceinline__ u16 f2bf(float x) {
    u32 u = __builtin_bit_cast(u32, x);
    u32 r = u + 0x7FFFu + ((u >> 16) & 1u);
    return (u16)(r >> 16);
}
__device__ __forceinline__ float bf2f(u16 u) {
    return __builtin_bit_cast(float, (u32)u << 16);
}
__device__ __forceinline__ u32 pack2(float a, float b) {
    return (u32)f2bf(a) | ((u32)f2bf(b) << 16);
}
__device__ __forceinline__ float sum8bf(uint4 v) {
    return bf2f((u16)(v.x & 0xffff)) + bf2f((u16)(v.x >> 16))
         + bf2f((u16)(v.y & 0xffff)) + bf2f((u16)(v.y >> 16))
         + bf2f((u16)(v.z & 0xffff)) + bf2f((u16)(v.z >> 16))
         + bf2f((u16)(v.w & 0xffff)) + bf2f((u16)(v.w >> 16));
}
__device__ __forceinline__ float dot8bf(uint4 v, const float* __restrict__ k) {
    const float4 k0 = *(const float4*)k;
    const float4 k1 = *(const float4*)(k + 4);
    return bf2f((u16)(v.x & 0xffff)) * k0.x + bf2f((u16)(v.x >> 16)) * k0.y
         + bf2f((u16)(v.y & 0xffff)) * k0.z + bf2f((u16)(v.y >> 16)) * k0.w
         + bf2f((u16)(v.z & 0xffff)) * k1.x + bf2f((u16)(v.z >> 16)) * k1.y
         + bf2f((u16)(v.w & 0xffff)) * k1.z + bf2f((u16)(v.w >> 16)) * k1.w;
}

// ---------------- weight prep ----------------
__global__ void cvt_bf16(const float* __restrict__ in, u16* __restrict__ out, int n)
{
    const int i = blockIdx.x * 256 + threadIdx.x;
    if (i < n) out[i] = f2bf(in[i]);
}

// in [L][R][C] fp32 -> out [L][C][R] bf16
__global__ void tr_bf16(const float* __restrict__ in, u16* __restrict__ out,
                        int R, int C, int total)
{
    const int i = blockIdx.x * 256 + threadIdx.x;
    if (i >= total) return;
    const int r = i % R;
    const int c = (i / R) % C;
    const int l = i / (R * C);
    out[i] = f2bf(in[((size_t)l * R + r) * C + c]);
}

// ================= MFMA bf16 GEMM (plain, bf16 A) =================
// C[M,N] = A[M,K] @ Bt[N,K]^T + bias
// mode 0: fp32 out ; mode 1: fp32 out + res ; mode 2: gelu -> bf16 out
__global__ __launch_bounds__(256) void gemm_bf16(
    const u16* __restrict__ A, const u16* __restrict__ Bt,
    const float* __restrict__ bias, const float* __restrict__ res,
    float* __restrict__ Cf, u16* __restrict__ Cb,
    int M, int N, int K, int mode)
{
    __shared__ u16 As[64][72];
    __shared__ u16 Bs[64][72];
    const int tid = threadIdx.x;
    const int lane = tid & 63, wave = tid >> 6;
    const int wr = wave & 1, wc = wave >> 1;
    const int l16 = lane & 15, quad = lane >> 4;
    const int m0 = blockIdx.y * 64, n0 = blockIdx.x * 64;
    const int srow = tid >> 2, skof = (tid & 3) * 16;

    floatx4 acc00 = {0.f,0.f,0.f,0.f}, acc01 = {0.f,0.f,0.f,0.f};
    floatx4 acc10 = {0.f,0.f,0.f,0.f}, acc11 = {0.f,0.f,0.f,0.f};

    const int gmA = m0 + srow;
    const bool mok = (gmA < M);
    const u16* ap = A + (size_t)gmA * K + skof;
    const u16* bp = Bt + (size_t)(n0 + srow) * K + skof;

    for (int k0 = 0; k0 < K; k0 += 64) {
        uint4 a0 = {0,0,0,0}, a1 = {0,0,0,0};
        if (mok) { a0 = *(const uint4*)(ap + k0); a1 = *(const uint4*)(ap + k0 + 8); }
        const uint4 b0 = *(const uint4*)(bp + k0);
        const uint4 b1 = *(const uint4*)(bp + k0 + 8);
        if (k0) __syncthreads();
        *(uint4*)&As[srow][skof]     = a0;
        *(uint4*)&As[srow][skof + 8] = a1;
        *(uint4*)&Bs[srow][skof]     = b0;
        *(uint4*)&Bs[srow][skof + 8] = b1;
        __syncthreads();
#pragma unroll
        for (int ks = 0; ks < 2; ++ks) {
            const short8 af0 = *(const short8*)&As[wr*32 + l16][ks*32 + quad*8];
            const short8 af1 = *(const short8*)&As[wr*32 + 16 + l16][ks*32 + quad*8];
            const short8 bf0 = *(const short8*)&Bs[wc*32 + l16][ks*32 + quad*8];
            const short8 bf1 = *(const short8*)&Bs[wc*32 + 16 + l16][ks*32 + quad*8];
            acc00 = __builtin_amdgcn_mfma_f32_16x16x32_bf16(af0, bf0, acc00, 0, 0, 0);
            acc01 = __builtin_amdgcn_mfma_f32_16x16x32_bf16(af0, bf1, acc01, 0, 0, 0);
            acc10 = __builtin_amdgcn_mfma_f32_16x16x32_bf16(af1, bf0, acc10, 0, 0, 0);
            acc11 = __builtin_amdgcn_mfma_f32_16x16x32_bf16(af1, bf1, acc11, 0, 0, 0);
        }
    }

    floatx4 accs[2][2] = {{acc00, acc01}, {acc10, acc11}};
    const int rbase = m0 + wr * 32 + quad * 4;
    const int cbase = n0 + wc * 32 + l16;
#pragma unroll
    for (int r = 0; r < 2; ++r) {
#pragma unroll
        for (int reg = 0; reg < 4; ++reg) {
            const int gm = rbase + r * 16 + reg;
            if (gm >= M) continue;
#pragma unroll
            for (int c = 0; c < 2; ++c) {
                const int gn = cbase + c * 16;
                float v = accs[r][c][reg] + bias[gn];
                if (mode == 1) v += res[(size_t)gm * N + gn];
                if (mode == 2) {
                    v = 0.5f * v * (1.f + erff(v * 0.70710678118654752f));
                    Cb[(size_t)gm * N + gn] = f2bf(v);
                } else {
                    Cf[(size_t)gm * N + gn] = v;
                }
            }
        }
    }
}

// ================= MFMA GEMM with fused LayerNorm on A (K=192, fp32 A) ==========
// C[M,N] = LN(A)[M,192] @ Bt[N,192]^T + bias ; mode 0: fp32 out ; mode 2: gelu->bf16
__global__ __launch_bounds__(256) void gemm_ln_bf16(
    const float* __restrict__ A, const u16* __restrict__ Bt,
    const float* __restrict__ lnw, const float* __restrict__ lnb,
    const float* __restrict__ bias,
    float* __restrict__ Cf, u16* __restrict__ Cb,
    int M, int N, int mode)
{
    __shared__ u16 As[64][72];
    __shared__ u16 Bs[64][72];
    const int tid = threadIdx.x;
    const int lane = tid & 63, wave = tid >> 6;
    const int wr = wave & 1, wc = wave >> 1;
    const int l16 = lane & 15, quad = lane >> 4;
    const int m0 = blockIdx.y * 64, n0 = blockIdx.x * 64;
    const int srow = tid >> 2, skof = (tid & 3) * 16;

    // ---- load full A row segment (48 fp32) + LN stats ----
    const int gmA = m0 + srow;                 // M == 197*64, always valid
    const float* arow = A + (size_t)gmA * 192 + skof;
    float4 xv[3][4];
    float s = 0.f, ss = 0.f;
#pragma unroll
    for (int c = 0; c < 3; ++c) {
#pragma unroll
        for (int j = 0; j < 4; ++j) {
            xv[c][j] = *(const float4*)(arow + c * 64 + j * 4);
            s  += xv[c][j].x + xv[c][j].y + xv[c][j].z + xv[c][j].w;
            ss += xv[c][j].x*xv[c][j].x + xv[c][j].y*xv[c][j].y
                + xv[c][j].z*xv[c][j].z + xv[c][j].w*xv[c][j].w;
        }
    }
    s  += __shfl_xor(s, 1);  s  += __shfl_xor(s, 2);
    ss += __shfl_xor(ss, 1); ss += __shfl_xor(ss, 2);
    const float mu = s * (1.f / 192.f);
    const float rstd = rsqrtf(ss * (1.f / 192.f) - mu * mu + 1e-5f);

    // ---- normalize, scale, pack to bf16 ----
    uint4 a_regs[3][2];
#pragma unroll
    for (int c = 0; c < 3; ++c) {
        u32 p[8];
#pragma unroll
        for (int j = 0; j < 4; ++j) {
            const int col = c * 64 + skof + j * 4;
            const float4 wv = *(const float4*)(lnw + col);
            const float4 bv = *(const float4*)(lnb + col);
            const float y0 = (xv[c][j].x - mu) * rstd * wv.x + bv.x;
            const float y1 = (xv[c][j].y - mu) * rstd * wv.y + bv.y;
            const float y2 = (xv[c][j].z - mu) * rstd * wv.z + bv.z;
            const float y3 = (xv[c][j].w - mu) * rstd * wv.w + bv.w;
            p[j * 2]     = pack2(y0, y1);
            p[j * 2 + 1] = pack2(y2, y3);
        }
        a_regs[c][0] = make_uint4(p[0], p[1], p[2], p[3]);
        a_regs[c][1] = make_uint4(p[4], p[5], p[6], p[7]);
    }

    floatx4 acc00 = {0.f,0.f,0.f,0.f}, acc01 = {0.f,0.f,0.f,0.f};
    floatx4 acc10 = {0.f,0.f,0.f,0.f}, acc11 = {0.f,0.f,0.f,0.f};
    const u16* bp = Bt + (size_t)(n0 + srow) * 192 + skof;

#pragma unroll
    for (int c = 0; c < 3; ++c) {
        const uint4 b0 = *(const uint4*)(bp + c * 64);
        const uint4 b1 = *(const uint4*)(bp + c * 64 + 8);
        if (c) __syncthreads();
        *(uint4*)&As[srow][skof]     = a_regs[c][0];
        *(uint4*)&As[srow][skof + 8] = a_regs[c][1];
        *(uint4*)&Bs[srow][skof]     = b0;
        *(uint4*)&Bs[srow][skof + 8] = b1;
        __syncthreads();
#pragma unroll
        for (int ks = 0; ks < 2; ++ks) {
            const short8 af0 = *(const short8*)&As[wr*32 + l16][ks*32 + quad*8];
            const short8 af1 = *(const short8*)&As[wr*32 + 16 + l16][ks*32 + quad*8];
            const short8 bf0 = *(const short8*)&Bs[wc*32 + l16][ks*32 + quad*8];
            const short8 bf1 = *(const short8*)&Bs[wc*32 + 16 + l16][ks*32 + quad*8];
            acc00 = __builtin_amdgcn_mfma_f32_16x16x32_bf16(af0, bf0, acc00, 0, 0, 0);
            acc01 = __builtin_amdgcn_mfma_f32_16x16x32_bf16(af0, bf1, acc01, 0, 0, 0);
            acc10 = __builtin_amdgcn_mfma_f32_16x16x32_bf16(af1, bf0, acc10, 0, 0, 0);
            acc11 = __builtin_amdgcn_mfma_f32_16x16x32_bf16(af1, bf1, acc11, 0, 0, 0);
        }
    }

    floatx4 accs[2][2] = {{acc00, acc01}, {acc10, acc11}};
    const int rbase = m0 + wr * 32 + quad * 4;
    const int cbase = n0 + wc * 32 + l16;
#pragma unroll
    for (int r = 0; r < 2; ++r) {
#pragma unroll
        for (int reg = 0; reg < 4; ++reg) {
            const int gm = rbase + r * 16 + reg;
#pragma unroll
            for (int c = 0; c < 2; ++c) {
                const int gn = cbase + c * 16;
                float v = accs[r][c][reg] + bias[gn];
                if (mode == 2) {
                    v = 0.5f * v * (1.f + erff(v * 0.70710678118654752f));
                    Cb[(size_t)gm * N + gn] = f2bf(v);
                } else {
                    Cf[(size_t)gm * N + gn] = v;
                }
            }
        }
    }
}

// ================= fused attention prep: fmap_pq / fmap_pkT / vT ==========
// grid (36, BHT): role 0-15 = pq tiles, 16-31 = pkT tiles, 32-35 = vT
__global__ __launch_bounds__(256) void attn_prep(
    const float* __restrict__ qkv, const u16* __restrict__ pmb,
    u16* __restrict__ pq_out, u16* __restrict__ pkT, u16* __restrict__ vT)
{
    __shared__ u16 As[64][72];
    __shared__ u16 Bs[64][72];
    __shared__ float nrm_s[64];
    const int tid = threadIdx.x;
    const int role = blockIdx.x;
    const int bh = blockIdx.y, b = bh / NH, h = bh % NH;

    if (role >= 32) {
        // ---- vT: transpose v[n][d] -> vT[d][n], zero-pad n>=197 ----
        float* ta = (float*)As;   // rows d 0..31, [32][65]
        float* tb = (float*)Bs;   // rows d 32..63
        const int n0 = (role - 32) * 64;
#pragma unroll
        for (int i = 0; i < 16; ++i) {
            const int idx = i * 256 + tid;
            const int n = idx >> 6, d = idx & 63;
            float v = 0.f;
            if (n0 + n < NTOK)
                v = qkv[(size_t)(b * NTOK + n0 + n) * 576 + 384 + h * 64 + d];
            if (d < 32) ta[d * 65 + n] = v; else tb[(d - 32) * 65 + n] = v;
        }
        __syncthreads();
#pragma unroll
        for (int i = 0; i < 16; ++i) {
            const int idx = i * 256 + tid;
            const int d = idx >> 6, n = idx & 63;
            const float v = (d < 32) ? ta[d * 65 + n] : tb[(d - 32) * 65 + n];
            vT[((size_t)bh * 64 + d) * 256 + n0 + n] = f2bf(v);
        }
        return;
    }

    const int lane = tid & 63, wave = tid >> 6;
    const int wr = wave & 1, wc = wave >> 1;
    const int l16 = lane & 15, quad = lane >> 4;
    const int srow = tid >> 2, skof = (tid & 3) * 16;
    const bool is_pq = (role < 16);
    const int rr = is_pq ? role : role - 16;
    const int m0 = (rr >> 2) * 64, n0 = (rr & 3) * 64;

    // token rows: for pq they are the A operand (m), for pkT the B operand (n)
    const int tokrow = (is_pq ? m0 : n0) + srow;
    const int soff = is_pq ? 0 : 192;
    uint4 t0 = {0,0,0,0}, t1 = {0,0,0,0};
    float sq = 0.f;
    if (tokrow < NTOK) {
        const float* tp = qkv + (size_t)(b * NTOK + tokrow) * 576 + soff + h * 64 + skof;
        const float4 f0 = *(const float4*)tp;
        const float4 f1 = *(const float4*)(tp + 4);
        const float4 f2 = *(const float4*)(tp + 8);
        const float4 f3 = *(const float4*)(tp + 12);
        t0.x = pack2(f0.x, f0.y); t0.y = pack2(f0.z, f0.w);
        t0.z = pack2(f1.x, f1.y); t0.w = pack2(f1.z, f1.w);
        t1.x = pack2(f2.x, f2.y); t1.y = pack2(f2.z, f2.w);
        t1.z = pack2(f3.x, f3.y); t1.w = pack2(f3.z, f3.w);
        sq = f0.x*f0.x + f0.y*f0.y + f0.z*f0.z + f0.w*f0.w
           + f1.x*f1.x + f1.y*f1.y + f1.z*f1.z + f1.w*f1.w
           + f2.x*f2.x + f2.y*f2.y + f2.z*f2.z + f2.w*f2.w
           + f3.x*f3.x + f3.y*f3.y + f3.z*f3.z + f3.w*f3.w;
    }
    sq += __shfl_xor(sq, 1);
    sq += __shfl_xor(sq, 2);
    if ((tid & 3) == 0) nrm_s[srow] = 0.5f * sq;

    // pm rows: B operand for pq (rows n0+), A operand for pkT (rows m0+)
    const int pmrow = (is_pq ? n0 : m0) + srow;
    const u16* pp = pmb + (size_t)pmrow * 64 + skof;
    const uint4 p0 = *(const uint4*)pp;
    const uint4 p1 = *(const uint4*)(pp + 8);

    if (is_pq) {
        *(uint4*)&As[srow][skof]     = t0;
        *(uint4*)&As[srow][skof + 8] = t1;
        *(uint4*)&Bs[srow][skof]     = p0;
        *(uint4*)&Bs[srow][skof + 8] = p1;
    } else {
        *(uint4*)&As[srow][skof]     = p0;
        *(uint4*)&As[srow][skof + 8] = p1;
        *(uint4*)&Bs[srow][skof]     = t0;
        *(uint4*)&Bs[srow][skof + 8] = t1;
    }
    __syncthreads();

    floatx4 acc00 = {0.f,0.f,0.f,0.f}, acc01 = {0.f,0.f,0.f,0.f};
    floatx4 acc10 = {0.f,0.f,0.f,0.f}, acc11 = {0.f,0.f,0.f,0.f};
#pragma unroll
    for (int ks = 0; ks < 2; ++ks) {
        const short8 af0 = *(const short8*)&As[wr*32 + l16][ks*32 + quad*8];
        const short8 af1 = *(const short8*)&As[wr*32 + 16 + l16][ks*32 + quad*8];
        const short8 bf0 = *(const short8*)&Bs[wc*32 + l16][ks*32 + quad*8];
        const short8 bf1 = *(const short8*)&Bs[wc*32 + 16 + l16][ks*32 + quad*8];
        acc00 = __builtin_amdgcn_mfma_f32_16x16x32_bf16(af0, bf0, acc00, 0, 0, 0);
        acc01 = __builtin_amdgcn_mfma_f32_16x16x32_bf16(af0, bf1, acc01, 0, 0, 0);
        acc10 = __builtin_amdgcn_mfma_f32_16x16x32_bf16(af1, bf0, acc10, 0, 0, 0);
        acc11 = __builtin_amdgcn_mfma_f32_16x16x32_bf16(af1, bf1, acc11, 0, 0, 0);
    }

    floatx4 accs[2][2] = {{acc00, acc01}, {acc10, acc11}};
    const float scale = 0.35355339059327373f;
    const int rbase = m0 + wr * 32 + quad * 4;
    const int cbase = n0 + wc * 32 + l16;
    if (is_pq) {
#pragma unroll
        for (int r = 0; r < 2; ++r) {
#pragma unroll
            for (int reg = 0; reg < 4; ++reg) {
                const int gr = rbase + r * 16 + reg;
                if (gr >= NTOK) continue;
                const float nr = nrm_s[gr - m0];
#pragma unroll
                for (int c = 0; c < 2; ++c) {
                    const int gn = cbase + c * 16;
                    pq_out[((size_t)bh * NTOK + gr) * 256 + gn] =
                        f2bf(__expf(accs[r][c][reg] - nr) * scale);
                }
            }
        }
    } else {
#pragma unroll
        for (int r = 0; r < 2; ++r) {
#pragma unroll
            for (int reg = 0; reg < 4; ++reg) {
                const int gm = rbase + r * 16 + reg;   // f row
#pragma unroll
                for (int c = 0; c < 2; ++c) {
                    const int gn = cbase + c * 16;     // n col
                    float v = 0.f;
                    if (gn < NTOK)
                        v = __expf(accs[r][c][reg] - nrm_s[gn - n0]) * scale;
                    pkT[((size_t)bh * 256 + gm) * 256 + gn] = f2bf(v);
                }
            }
        }
    }
}

// ---------------- KVT[d][f] = sum_n vT[d][n]*pkT[f][n] + fused ksum[f] ----------------
__global__ __launch_bounds__(256) void kv_mfma(
    const u16* __restrict__ vT, const u16* __restrict__ pkT,
    u16* __restrict__ kvT, float* __restrict__ ksum)
{
    __shared__ u16 As[64][72];
    __shared__ u16 Bs[64][72];
    const int tid = threadIdx.x;
    const int lane = tid & 63, wave = tid >> 6;
    const int wr = wave & 1, wc = wave >> 1;
    const int l16 = lane & 15, quad = lane >> 4;
    const int bh = blockIdx.y;
    const int n0 = blockIdx.x * 64;
    const int srow = tid >> 2, skof = (tid & 3) * 16;

    floatx4 acc00 = {0.f,0.f,0.f,0.f}, acc01 = {0.f,0.f,0.f,0.f};
    floatx4 acc10 = {0.f,0.f,0.f,0.f}, acc11 = {0.f,0.f,0.f,0.f};
    float ksp = 0.f;

    const u16* ap = vT  + ((size_t)bh * 64 + srow) * 256 + skof;
    const u16* bp = pkT + ((size_t)bh * 256 + n0 + srow) * 256 + skof;

    for (int k0 = 0; k0 < 256; k0 += 64) {
        const uint4 a0 = *(const uint4*)(ap + k0);
        const uint4 a1 = *(const uint4*)(ap + k0 + 8);
        const uint4 b0 = *(const uint4*)(bp + k0);
        const uint4 b1 = *(const uint4*)(bp + k0 + 8);
        ksp += sum8bf(b0) + sum8bf(b1);
        if (k0) __syncthreads();
        *(uint4*)&As[srow][skof]     = a0;
        *(uint4*)&As[srow][skof + 8] = a1;
        *(uint4*)&Bs[srow][skof]     = b0;
        *(uint4*)&Bs[srow][skof + 8] = b1;
        __syncthreads();
#pragma unroll
        for (int ks = 0; ks < 2; ++ks) {
            const short8 af0 = *(const short8*)&As[wr*32 + l16][ks*32 + quad*8];
            const short8 af1 = *(const short8*)&As[wr*32 + 16 + l16][ks*32 + quad*8];
            const short8 bf0 = *(const short8*)&Bs[wc*32 + l16][ks*32 + quad*8];
            const short8 bf1 = *(const short8*)&Bs[wc*32 + 16 + l16][ks*32 + quad*8];
            acc00 = __builtin_amdgcn_mfma_f32_16x16x32_bf16(af0, bf0, acc00, 0, 0, 0);
            acc01 = __builtin_amdgcn_mfma_f32_16x16x32_bf16(af0, bf1, acc01, 0, 0, 0);
            acc10 = __builtin_amdgcn_mfma_f32_16x16x32_bf16(af1, bf0, acc10, 0, 0, 0);
            acc11 = __builtin_amdgcn_mfma_f32_16x16x32_bf16(af1, bf1, acc11, 0, 0, 0);
        }
    }

    ksp += __shfl_xor(ksp, 1);
    ksp += __shfl_xor(ksp, 2);
    if ((tid & 3) == 0) ksum[bh * 256 + n0 + srow] = ksp;

    floatx4 accs[2][2] = {{acc00, acc01}, {acc10, acc11}};
    const int rbase = wr * 32 + quad * 4;          // d row (<64)
    const int cbase = n0 + wc * 32 + l16;          // f col
#pragma unroll
    for (int r = 0; r < 2; ++r) {
#pragma unroll
        for (int reg = 0; reg < 4; ++reg) {
            const int gm = rbase + r * 16 + reg;
#pragma unroll
            for (int c = 0; c < 2; ++c) {
                const int gn = cbase + c * 16;
                kvT[((size_t)bh * 64 + gm) * 256 + gn] = f2bf(accs[r][c][reg]);
            }
        }
    }
}

// ---------------- attn: out[n][d] = (pq[n].KVT[d]) * dinv[n], dinv fused ----------------
__global__ __launch_bounds__(256) void attn_mfma(
    const u16* __restrict__ pq, const u16* __restrict__ kvT,
    const float* __restrict__ ksum, u16* __restrict__ attn_o)
{
    __shared__ u16 As[64][72];
    __shared__ u16 Bs[64][72];
    __shared__ float dinv_s[64];
    const int tid = threadIdx.x;
    const int lane = tid & 63, wave = tid >> 6;
    const int wr = wave & 1, wc = wave >> 1;
    const int l16 = lane & 15, quad = lane >> 4;
    const int bh = blockIdx.y, b = bh / NH, h = bh % NH;
    const int m0 = blockIdx.x * 64;
    const int srow = tid >> 2, skof = (tid & 3) * 16;

    floatx4 acc00 = {0.f,0.f,0.f,0.f}, acc01 = {0.f,0.f,0.f,0.f};
    floatx4 acc10 = {0.f,0.f,0.f,0.f}, acc11 = {0.f,0.f,0.f,0.f};
    float den = 0.f;

    const int gmA = m0 + srow;
    const bool mok = (gmA < NTOK);
    const u16* ap = pq  + ((size_t)bh * NTOK + gmA) * 256 + skof;
    const u16* bp = kvT + ((size_t)bh * 64 + srow) * 256 + skof;
    const float* ks = ksum + bh * 256 + skof;

    for (int k0 = 0; k0 < 256; k0 += 64) {
        uint4 a0 = {0,0,0,0}, a1 = {0,0,0,0};
        if (mok) {
            a0 = *(const uint4*)(ap + k0);
            a1 = *(const uint4*)(ap + k0 + 8);
            den += dot8bf(a0, ks + k0) + dot8bf(a1, ks + k0 + 8);
        }
        const uint4 b0 = *(const uint4*)(bp + k0);
        const uint4 b1 = *(const uint4*)(bp + k0 + 8);
        if (k0) __syncthreads();
        *(uint4*)&As[srow][skof]     = a0;
        *(uint4*)&As[srow][skof + 8] = a1;
        *(uint4*)&Bs[srow][skof]     = b0;
        *(uint4*)&Bs[srow][skof + 8] = b1;
        __syncthreads();
#pragma unroll
        for (int ks2 = 0; ks2 < 2; ++ks2) {
            const short8 af0 = *(const short8*)&As[wr*32 + l16][ks2*32 + quad*8];
            const short8 af1 = *(const short8*)&As[wr*32 + 16 + l16][ks2*32 + quad*8];
            const short8 bf0 = *(const short8*)&Bs[wc*32 + l16][ks2*32 + quad*8];
            const short8 bf1 = *(const short8*)&Bs[wc*32 + 16 + l16][ks2*32 + quad*8];
            acc00 = __builtin_amdgcn_mfma_f32_16x16x32_bf16(af0, bf0, acc00, 0, 0, 0);
            acc01 = __builtin_amdgcn_mfma_f32_16x16x32_bf16(af0, bf1, acc01, 0, 0, 0);
            acc10 = __builtin_amdgcn_mfma_f32_16x16x32_bf16(af1, bf0, acc10, 0, 0, 0);
            acc11 = __builtin_amdgcn_mfma_f32_16x16x32_bf16(af1, bf1, acc11, 0, 0, 0);
        }
    }

    den += __shfl_xor(den, 1);
    den += __shfl_xor(den, 2);
    if ((tid & 3) == 0) dinv_s[srow] = 1.f / den;
    __syncthreads();

    floatx4 accs[2][2] = {{acc00, acc01}, {acc10, acc11}};
    const int rbase = m0 + wr * 32 + quad * 4;     // n row
    const int cbase = wc * 32 + l16;               // d col (<64)
#pragma unroll
    for (int r = 0; r < 2; ++r) {
#pragma unroll
        for (int reg = 0; reg < 4; ++reg) {
            const int gm = rbase + r * 16 + reg;
            if (gm >= NTOK) continue;
            const float di = dinv_s[gm - m0];
#pragma unroll
            for (int c = 0; c < 2; ++c) {
                const int gn = cbase + c * 16;
                attn_o[((size_t)(b * NTOK + gm)) * EMB + h * 64 + gn] =
                    f2bf(accs[r][c][reg] * di);
            }
        }
    }
}

// ---------------- im2col (bf16 out) ----------------
__global__ void im2col_kernel(const float* __restrict__ x, u16* __restrict__ p, int total)
{
    const int i = blockIdx.x * 256 + threadIdx.x;
    if (i >= total) return;
    const int col = i % 768, row = i / 768;
    const int px = col & 15, py = (col >> 4) & 15, c = col >> 8;
    const int gx = row % 14, gy = (row / 14) % 14, b = row / 196;
    p[i] = f2bf(x[((size_t)(b * 3 + c) * 224 + gy * 16 + py) * 224 + gx * 16 + px]);
}

// ---------------- patch-embed finish ----------------
__global__ void embed_finish(const float* __restrict__ tok, const float* __restrict__ cls,
                             const float* __restrict__ pos, const float* __restrict__ w,
                             const float* __restrict__ b, float* __restrict__ h)
{
    const int wid = threadIdx.x >> 6, lane = threadIdx.x & 63;
    const int r = blockIdx.x * 4 + wid;
    if (r >= MTOT) return;
    const int bb = r / NTOK, t = r % NTOK;
    float* q = h + (size_t)r * EMB;
    if (t == 0) {
        q[lane]       = cls[lane]       + pos[lane];
        q[lane + 64]  = cls[lane + 64]  + pos[lane + 64];
        q[lane + 128] = cls[lane + 128] + pos[lane + 128];
        return;
    }
    const float* p = tok + ((size_t)bb * NPATCH + (t - 1)) * EMB;
    float x0 = p[lane], x1 = p[lane + 64], x2 = p[lane + 128];
    float s = x0 + x1 + x2;
#pragma unroll
    for (int off = 32; off; off >>= 1) s += __shfl_xor(s, off);
    const float mu = s * (1.f / 192.f);
    const float d0 = x0 - mu, d1 = x1 - mu, d2 = x2 - mu;
    float v = d0 * d0 + d1 * d1 + d2 * d2;
#pragma unroll
    for (int off = 32; off; off >>= 1) v += __shfl_xor(v, off);
    const float rstd = rsqrtf(v * (1.f / 192.f) + 1e-5f);
    const float* pr = pos + (size_t)t * EMB;
    q[lane]       = d0 * rstd * w[lane]       + b[lane]       + pr[lane];
    q[lane + 64]  = d1 * rstd * w[lane + 64]  + b[lane + 64]  + pr[lane + 64];
    q[lane + 128] = d2 * rstd * w[lane + 128] + b[lane + 128] + pr[lane + 128];
}

// ---------------- LayerNorm over 192 (final head only) ----------------
__global__ void ln192(const float* __restrict__ in, int in_stride,
                      const float* __restrict__ w, const float* __restrict__ b,
                      float* __restrict__ outf, int rows)
{
    const int wid = threadIdx.x >> 6, lane = threadIdx.x & 63;
    const int r = blockIdx.x * 4 + wid;
    if (r >= rows) return;
    const float* p = in + (size_t)r * in_stride;
    float x0 = p[lane], x1 = p[lane + 64], x2 = p[lane + 128];
    float s = x0 + x1 + x2;
#pragma unroll
    for (int off = 32; off; off >>= 1) s += __shfl_xor(s, off);
    const float mu = s * (1.f / 192.f);
    const float d0 = x0 - mu, d1 = x1 - mu, d2 = x2 - mu;
    float v = d0 * d0 + d1 * d1 + d2 * d2;
#pragma unroll
    for (int off = 32; off; off >>= 1) v += __shfl_xor(v, off);
    const float rstd = rsqrtf(v * (1.f / 192.f) + 1e-5f);
    float* q = outf + (size_t)r * EMB;
    q[lane]       = d0 * rstd * w[lane]       + b[lane];
    q[lane + 64]  = d1 * rstd * w[lane + 64]  + b[lane + 64];
    q[lane + 128] = d2 * rstd * w[lane + 128] + b[lane + 128];
}

// ---------------- fp32 GEMM (head / exits only) ----------------
__global__ __launch_bounds__(256) void gemm_f32(
    const float* __restrict__ A, const float* __restrict__ Bm,
    const float* __restrict__ bias, float* __restrict__ C,
    int M, int N, int K)
{
    __shared__ float As[16][68];
    __shared__ float Bs[16][64];
    const int tid = threadIdx.x;
    const int tx = tid & 15, ty = tid >> 4;
    const int m0 = blockIdx.y * 64, n0 = blockIdx.x * 64;
    float acc[4][4] = {};

    for (int k0 = 0; k0 < K; k0 += 16) {
        {
            const int c = tid & 15, r4 = tid >> 4;
#pragma unroll
            for (int i = 0; i < 4; ++i) {
                const int r = r4 + i * 16, gm = m0 + r;
                As[c][r] = (gm < M) ? A[(size_t)gm * K + (k0 + c)] : 0.f;
            }
        }
        {
            const int cb = tid & 63, rb4 = tid >> 6;
#pragma unroll
            for (int i = 0; i < 4; ++i) {
                const int rb = rb4 + i * 4;
                const int gn = n0 + cb;
                Bs[rb][cb] = (gn < N) ? Bm[(size_t)(k0 + rb) * N + gn] : 0.f;
            }
        }
        __syncthreads();
#pragma unroll
        for (int kk = 0; kk < 16; ++kk) {
            const float4 av = *reinterpret_cast<const float4*>(&As[kk][ty * 4]);
            const float4 bv = *reinterpret_cast<const float4*>(&Bs[kk][tx * 4]);
            const float a_[4] = {av.x, av.y, av.z, av.w};
            const float b_[4] = {bv.x, bv.y, bv.z, bv.w};
#pragma unroll
            for (int i2 = 0; i2 < 4; ++i2)
#pragma unroll
                for (int j2 = 0; j2 < 4; ++j2)
                    acc[i2][j2] = fmaf(a_[i2], b_[j2], acc[i2][j2]);
        }
        __syncthreads();
    }

#pragma unroll
    for (int i = 0; i < 4; ++i) {
        const int gm = m0 + ty * 4 + i;
        if (gm >= M) continue;
#pragma unroll
        for (int j = 0; j < 4; ++j) {
            const int gn = n0 + tx * 4 + j;
            if (gn >= N) continue;
            C[(size_t)gm * N + gn] = acc[i][j] + bias[gn];
        }
    }
}

// ---------------- mean over tokens for exits ----------------
__global__ void pool_kernel(const float* __restrict__ h, float* __restrict__ pooled)
{
    const int b = blockIdx.x, e = threadIdx.x;  // block 192
    float s = 0.f;
    for (int n = 0; n < NTOK; ++n) s += h[((size_t)(b * NTOK + n)) * EMB + e];
    pooled[b * EMB + e] = s * (1.f / 197.f);
}

// ---------------- host launch ----------------
extern "C" void kernel_launch(void* const* d_in, const int* in_sizes, int n_in,
                              void* d_out, int out_size, void* d_ws, size_t ws_size,
                              hipStream_t stream)
{
    const float* x          = (const float*)d_in[0];
    const float* patch_w    = (const float*)d_in[1];
    const float* patch_b    = (const float*)d_in[2];
    const float* pe_norm_w  = (const float*)d_in[3];
    const float* pe_norm_b  = (const float*)d_in[4];
    const float* cls_token  = (const float*)d_in[5];
    const float* pos_embed  = (const float*)d_in[6];
    const float* norm1_w    = (const float*)d_in[7];
    const float* norm1_b    = (const float*)d_in[8];
    const float* qkv_w      = (const float*)d_in[9];
    const float* qkv_b      = (const float*)d_in[10];
    const float* proj_mat   = (const float*)d_in[11];
    const float* attn_pw    = (const float*)d_in[12];
    const float* attn_pb    = (const float*)d_in[13];
    const float* norm2_w    = (const float*)d_in[14];
    const float* norm2_b    = (const float*)d_in[15];
    const float* fc1_w      = (const float*)d_in[16];
    const float* fc1_b      = (const float*)d_in[17];
    const float* fc2_w      = (const float*)d_in[18];
    const float* fc2_b      = (const float*)d_in[19];
    const float* exit_w     = (const float*)d_in[20];
    const float* exit_b     = (const float*)d_in[21];
    const float* fnorm_w    = (const float*)d_in[22];
    const float* fnorm_b    = (const float*)d_in[23];
    const float* head_w     = (const float*)d_in[24];
    const float* head_b     = (const float*)d_in[25];
    float* out = (float*)d_out;

    float* ws = (float*)d_ws;
    // workspace layout (float-slot offsets)
    float* H     = ws + 0;                  // 2,420,736
    float* QKV   = ws + 2420736;            // 7,262,208
    u16*   PQb   = (u16*)(ws + 9682944);    // 192*197*256 bf16
    u16*   PKT   = (u16*)(ws + 14524416);   // 192*256*256 bf16
    u16*   VT    = (u16*)(ws + 20815872);   // 192*64*256 bf16
    u16*   KVT   = (u16*)(ws + 22388736);   // 192*64*256 bf16
    u16*   MIDB  = (u16*)(ws + 23961600);   // 12608*768 bf16
    u16*   ATNB  = (u16*)(ws + 30013440);   // 12608*192 bf16
    float* XLNF  = ws + 31223808;           // 64*192
    float* POOL  = ws + 31236096;           // 64*192
    float* KSUM  = ws + 31248384;           // 192*256
    u16*   QKVWT = (u16*)(ws + 31297536);   // 12*576*192 bf16
    u16*   APWT  = (u16*)(ws + 31961088);   // 12*192*192 bf16
    u16*   F1WT  = (u16*)(ws + 32182272);   // 12*768*192 bf16
    u16*   F2WT  = (u16*)(ws + 33067008);   // 12*192*768 bf16
    u16*   PATWB = (u16*)(ws + 33951744);   // 192*768 bf16
    u16*   PMB   = (u16*)(ws + 34025472);   // 12*256*64 bf16
    // aliases (disjoint lifetimes)
    u16*   P_IMB = MIDB;   // im2col [12544,768] bf16 (prologue only)
    float* TOK   = QKV;    // patch tokens [12544,192] f32 (prologue only)

    if (ws_size < (size_t)34123776 * sizeof(float)) return;

    // ---- weight prep ----
    cvt_bf16<<<(147456 + 255) / 256, 256, 0, stream>>>(patch_w, PATWB, 147456);
    cvt_bf16<<<(196608 + 255) / 256, 256, 0, stream>>>(proj_mat, PMB, 196608);
    tr_bf16<<<(1327104 + 255) / 256, 256, 0, stream>>>(qkv_w,   QKVWT, 192, 576, 1327104);
    tr_bf16<<<(442368 + 255) / 256, 256, 0, stream>>>(attn_pw, APWT,  192, 192, 442368);
    tr_bf16<<<(1769472 + 255) / 256, 256, 0, stream>>>(fc1_w,   F1WT,  192, 768, 1769472);
    tr_bf16<<<(1769472 + 255) / 256, 256, 0, stream>>>(fc2_w,   F2WT,  768, 192, 1769472);

    // ---- patch embed ----
    im2col_kernel<<<(MPAT * 768 + 255) / 256, 256, 0, stream>>>(x, P_IMB, MPAT * 768);
    gemm_bf16<<<dim3(3, 196), 256, 0, stream>>>(P_IMB, PATWB, patch_b, nullptr,
                                                TOK, nullptr, MPAT, EMB, 768, 0);
    embed_finish<<<(MTOT + 3) / 4, 256, 0, stream>>>(TOK, cls_token, pos_embed,
                                                     pe_norm_w, pe_norm_b, H);

    // ---- transformer layers ----
    for (int i = 0; i < 12; ++i) {
        const u16* qwt  = QKVWT + (size_t)i * 576 * 192;
        const u16* pwt  = APWT  + (size_t)i * 192 * 192;
        const u16* f1wt = F1WT  + (size_t)i * 768 * 192;
        const u16* f2wt = F2WT  + (size_t)i * 192 * 768;
        const u16* pmb  = PMB   + (size_t)i * 256 * 64;
        const float* qb  = qkv_b   + (size_t)i * 576;
        const float* pb  = attn_pb + (size_t)i * 192;
        const float* f1b = fc1_b   + (size_t)i * 768;
        const float* f2b = fc2_b   + (size_t)i * 192;

        gemm_ln_bf16<<<dim3(9, 197), 256, 0, stream>>>(
            H, qwt, norm1_w + i * EMB, norm1_b + i * EMB, qb,
            QKV, nullptr, MTOT, 576, 0);
        attn_prep<<<dim3(36, BHT), 256, 0, stream>>>(QKV, pmb, PQb, PKT, VT);
        kv_mfma<<<dim3(4, BHT), 256, 0, stream>>>(VT, PKT, KVT, KSUM);
        attn_mfma<<<dim3(4, BHT), 256, 0, stream>>>(PQb, KVT, KSUM, ATNB);
        gemm_bf16<<<dim3(3, 197), 256, 0, stream>>>(ATNB, pwt, pb, H,
                                                    H, nullptr, MTOT, EMB, EMB, 1);
        gemm_ln_bf16<<<dim3(12, 197), 256, 0, stream>>>(
            H, f1wt, norm2_w + i * EMB, norm2_b + i * EMB, f1b,
            nullptr, MIDB, MTOT, MLPD, 2);
        gemm_bf16<<<dim3(3, 197), 256, 0, stream>>>(MIDB, f2wt, f2b, H,
                                                    H, nullptr, MTOT, EMB, MLPD, 1);

        const int e = (i == 3) ? 0 : (i == 7) ? 1 : (i == 11) ? 2 : -1;
        if (e >= 0) {
            pool_kernel<<<BB, 192, 0, stream>>>(H, POOL);
            gemm_f32<<<dim3(16, 1), 256, 0, stream>>>(POOL, exit_w + (size_t)e * 192 * 1000,
                                                      exit_b + (size_t)e * 1000,
                                                      out + (size_t)(1 + e) * BB * NCLS,
                                                      BB, NCLS, EMB);
        }
    }

    // ---- head ----
    ln192<<<(BB + 3) / 4, 256, 0, stream>>>(H, NTOK * EMB, fnorm_w, fnorm_b, XLNF, BB);
    gemm_f32<<<dim3(16, 1), 256, 0, stream>>>(XLNF, head_w, head_b, out, BB, NCLS, EMB);
}

// Round 6
// 1824.717 us; speedup vs baseline: 1.2151x; 1.2151x over previous
//
#include <hip/hip_runtime.h>
#include <math.h>

typedef unsigned short u16;
typedef unsigned int u32;
typedef __attribute__((ext_vector_type(8))) short short8;
typedef __attribute__((ext_vector_type(4))) float floatx4;

// ---------------- problem constants ----------------
#define BB 64
#define NTOK 197
#define NPATCH 196
#define EMB 192
#define NH 3
#define HD 64
#define FEAT 256
#define MLPD 768
#define NCLS 1000
#define MTOT (BB*NTOK)      // 12608
#define MPAT (BB*NPATCH)    // 12544
#define BHT (BB*NH)         // 192

// ---------------- bf16 helpers ----------------
__device__ __forceinline__ u16 f2bf(float x) {
    u32 u = __builtin_bit_cast(u32, x);
    u32 r = u + 0x7FFFu + ((u >> 16) & 1u);
    return (u16)(r >> 16);
}
__device__ __forceinline__ float bf2f(u16 u) {
    return __builtin_bit_cast(float, (u32)u << 16);
}
__device__ __forceinline__ float sum8bf(uint4 v) {
    return bf2f((u16)(v.x & 0xffff)) + bf2f((u16)(v.x >> 16))
         + bf2f((u16)(v.y & 0xffff)) + bf2f((u16)(v.y >> 16))
         + bf2f((u16)(v.z & 0xffff)) + bf2f((u16)(v.z >> 16))
         + bf2f((u16)(v.w & 0xffff)) + bf2f((u16)(v.w >> 16));
}
__device__ __forceinline__ float sqr8bf(uint4 v) {
    float s = 0.f;
    float t;
    t = bf2f((u16)(v.x & 0xffff)); s += t*t;  t = bf2f((u16)(v.x >> 16)); s += t*t;
    t = bf2f((u16)(v.y & 0xffff)); s += t*t;  t = bf2f((u16)(v.y >> 16)); s += t*t;
    t = bf2f((u16)(v.z & 0xffff)); s += t*t;  t = bf2f((u16)(v.z >> 16)); s += t*t;
    t = bf2f((u16)(v.w & 0xffff)); s += t*t;  t = bf2f((u16)(v.w >> 16)); s += t*t;
    return s;
}
__device__ __forceinline__ float dot8bf(uint4 v, const float* __restrict__ k) {
    const float4 k0 = *(const float4*)k;
    const float4 k1 = *(const float4*)(k + 4);
    return bf2f((u16)(v.x & 0xffff)) * k0.x + bf2f((u16)(v.x >> 16)) * k0.y
         + bf2f((u16)(v.y & 0xffff)) * k0.z + bf2f((u16)(v.y >> 16)) * k0.w
         + bf2f((u16)(v.z & 0xffff)) * k1.x + bf2f((u16)(v.z >> 16)) * k1.y
         + bf2f((u16)(v.w & 0xffff)) * k1.z + bf2f((u16)(v.w >> 16)) * k1.w;
}

// ---------------- weight prep ----------------
__global__ void cvt_bf16(const float* __restrict__ in, u16* __restrict__ out, int n)
{
    const int i = blockIdx.x * 256 + threadIdx.x;
    if (i < n) out[i] = f2bf(in[i]);
}

// in [L][R][C] fp32 -> out [L][C][R] bf16
__global__ void tr_bf16(const float* __restrict__ in, u16* __restrict__ out,
                        int R, int C, int total)
{
    const int i = blockIdx.x * 256 + threadIdx.x;
    if (i >= total) return;
    const int r = i % R;
    const int c = (i / R) % C;
    const int l = i / (R * C);
    out[i] = f2bf(in[((size_t)l * R + r) * C + c]);
}

// ================= MFMA bf16 GEMM =================
// C[M,N] = A[M,K] @ Bt[N,K]^T + bias
// mode 0: fp32 out ; mode 1: fp32 out + res ; mode 2: gelu -> bf16 out ; mode 3: bf16 out
__global__ __launch_bounds__(256) void gemm_bf16(
    const u16* __restrict__ A, const u16* __restrict__ Bt,
    const float* __restrict__ bias, const float* __restrict__ res,
    float* __restrict__ Cf, u16* __restrict__ Cb,
    int M, int N, int K, int mode)
{
    __shared__ u16 As[64][72];
    __shared__ u16 Bs[64][72];
    const int tid = threadIdx.x;
    const int lane = tid & 63, wave = tid >> 6;
    const int wr = wave & 1, wc = wave >> 1;
    const int l16 = lane & 15, quad = lane >> 4;
    const int m0 = blockIdx.y * 64, n0 = blockIdx.x * 64;
    const int srow = tid >> 2, skof = (tid & 3) * 16;

    floatx4 acc00 = {0.f,0.f,0.f,0.f}, acc01 = {0.f,0.f,0.f,0.f};
    floatx4 acc10 = {0.f,0.f,0.f,0.f}, acc11 = {0.f,0.f,0.f,0.f};

    const int gmA = m0 + srow;
    const bool mok = (gmA < M);
    const u16* ap = A + (size_t)gmA * K + skof;
    const u16* bp = Bt + (size_t)(n0 + srow) * K + skof;

    for (int k0 = 0; k0 < K; k0 += 64) {
        uint4 a0 = {0,0,0,0}, a1 = {0,0,0,0};
        if (mok) { a0 = *(const uint4*)(ap + k0); a1 = *(const uint4*)(ap + k0 + 8); }
        const uint4 b0 = *(const uint4*)(bp + k0);
        const uint4 b1 = *(const uint4*)(bp + k0 + 8);
        if (k0) __syncthreads();
        *(uint4*)&As[srow][skof]     = a0;
        *(uint4*)&As[srow][skof + 8] = a1;
        *(uint4*)&Bs[srow][skof]     = b0;
        *(uint4*)&Bs[srow][skof + 8] = b1;
        __syncthreads();
#pragma unroll
        for (int ks = 0; ks < 2; ++ks) {
            const short8 af0 = *(const short8*)&As[wr*32 + l16][ks*32 + quad*8];
            const short8 af1 = *(const short8*)&As[wr*32 + 16 + l16][ks*32 + quad*8];
            const short8 bf0 = *(const short8*)&Bs[wc*32 + l16][ks*32 + quad*8];
            const short8 bf1 = *(const short8*)&Bs[wc*32 + 16 + l16][ks*32 + quad*8];
            acc00 = __builtin_amdgcn_mfma_f32_16x16x32_bf16(af0, bf0, acc00, 0, 0, 0);
            acc01 = __builtin_amdgcn_mfma_f32_16x16x32_bf16(af0, bf1, acc01, 0, 0, 0);
            acc10 = __builtin_amdgcn_mfma_f32_16x16x32_bf16(af1, bf0, acc10, 0, 0, 0);
            acc11 = __builtin_amdgcn_mfma_f32_16x16x32_bf16(af1, bf1, acc11, 0, 0, 0);
        }
    }

    floatx4 accs[2][2] = {{acc00, acc01}, {acc10, acc11}};
    const int rbase = m0 + wr * 32 + quad * 4;
    const int cbase = n0 + wc * 32 + l16;
#pragma unroll
    for (int r = 0; r < 2; ++r) {
#pragma unroll
        for (int reg = 0; reg < 4; ++reg) {
            const int gm = rbase + r * 16 + reg;
            if (gm >= M) continue;
#pragma unroll
            for (int c = 0; c < 2; ++c) {
                const int gn = cbase + c * 16;
                float v = accs[r][c][reg] + bias[gn];
                if (mode == 1) v += res[(size_t)gm * N + gn];
                if (mode == 2) {
                    v = 0.5f * v * (1.f + erff(v * 0.70710678118654752f));
                    Cb[(size_t)gm * N + gn] = f2bf(v);
                } else if (mode == 3) {
                    Cb[(size_t)gm * N + gn] = f2bf(v);
                } else {
                    Cf[(size_t)gm * N + gn] = v;
                }
            }
        }
    }
}

// ================= fused attention prep: fmap_pq / fmap_pkT / vT ==========
// qkv is bf16 [B*NTOK][576]; grid (36, BHT): 0-15 pq tiles, 16-31 pkT tiles, 32-35 vT
__global__ __launch_bounds__(256) void attn_prep(
    const u16* __restrict__ qkv, const u16* __restrict__ pmb,
    u16* __restrict__ pq_out, u16* __restrict__ pkT, u16* __restrict__ vT)
{
    __shared__ u16 As[64][72];
    __shared__ u16 Bs[64][72];
    __shared__ float nrm_s[64];
    const int tid = threadIdx.x;
    const int role = blockIdx.x;
    const int bh = blockIdx.y, b = bh / NH, h = bh % NH;

    if (role >= 32) {
        // ---- vT: transpose v[n][d] -> vT[d][n], zero-pad n>=197 (bf16 throughout) ----
        u16* t = (u16*)As;   // [64][66] u16 = 8448 B, fits in As
        const int n0 = (role - 32) * 64;
#pragma unroll
        for (int i = 0; i < 16; ++i) {
            const int idx = i * 256 + tid;
            const int n = idx >> 6, d = idx & 63;
            u16 v = 0;
            if (n0 + n < NTOK)
                v = qkv[(size_t)(b * NTOK + n0 + n) * 576 + 384 + h * 64 + d];
            t[d * 66 + n] = v;
        }
        __syncthreads();
#pragma unroll
        for (int i = 0; i < 16; ++i) {
            const int idx = i * 256 + tid;
            const int d = idx >> 6, n = idx & 63;
            vT[((size_t)bh * 64 + d) * 256 + n0 + n] = t[d * 66 + n];
        }
        return;
    }

    const int lane = tid & 63, wave = tid >> 6;
    const int wr = wave & 1, wc = wave >> 1;
    const int l16 = lane & 15, quad = lane >> 4;
    const int srow = tid >> 2, skof = (tid & 3) * 16;
    const bool is_pq = (role < 16);
    const int rr = is_pq ? role : role - 16;
    const int m0 = (rr >> 2) * 64, n0 = (rr & 3) * 64;

    // token rows: A operand for pq (m), B operand for pkT (n)
    const int tokrow = (is_pq ? m0 : n0) + srow;
    const int soff = is_pq ? 0 : 192;
    uint4 t0 = {0,0,0,0}, t1 = {0,0,0,0};
    float sq = 0.f;
    if (tokrow < NTOK) {
        const u16* tp = qkv + (size_t)(b * NTOK + tokrow) * 576 + soff + h * 64 + skof;
        t0 = *(const uint4*)tp;
        t1 = *(const uint4*)(tp + 8);
        sq = sqr8bf(t0) + sqr8bf(t1);
    }
    sq += __shfl_xor(sq, 1);
    sq += __shfl_xor(sq, 2);
    if ((tid & 3) == 0) nrm_s[srow] = 0.5f * sq;

    const int pmrow = (is_pq ? n0 : m0) + srow;
    const u16* pp = pmb + (size_t)pmrow * 64 + skof;
    const uint4 p0 = *(const uint4*)pp;
    const uint4 p1 = *(const uint4*)(pp + 8);

    if (is_pq) {
        *(uint4*)&As[srow][skof]     = t0;
        *(uint4*)&As[srow][skof + 8] = t1;
        *(uint4*)&Bs[srow][skof]     = p0;
        *(uint4*)&Bs[srow][skof + 8] = p1;
    } else {
        *(uint4*)&As[srow][skof]     = p0;
        *(uint4*)&As[srow][skof + 8] = p1;
        *(uint4*)&Bs[srow][skof]     = t0;
        *(uint4*)&Bs[srow][skof + 8] = t1;
    }
    __syncthreads();

    floatx4 acc00 = {0.f,0.f,0.f,0.f}, acc01 = {0.f,0.f,0.f,0.f};
    floatx4 acc10 = {0.f,0.f,0.f,0.f}, acc11 = {0.f,0.f,0.f,0.f};
#pragma unroll
    for (int ks = 0; ks < 2; ++ks) {
        const short8 af0 = *(const short8*)&As[wr*32 + l16][ks*32 + quad*8];
        const short8 af1 = *(const short8*)&As[wr*32 + 16 + l16][ks*32 + quad*8];
        const short8 bf0 = *(const short8*)&Bs[wc*32 + l16][ks*32 + quad*8];
        const short8 bf1 = *(const short8*)&Bs[wc*32 + 16 + l16][ks*32 + quad*8];
        acc00 = __builtin_amdgcn_mfma_f32_16x16x32_bf16(af0, bf0, acc00, 0, 0, 0);
        acc01 = __builtin_amdgcn_mfma_f32_16x16x32_bf16(af0, bf1, acc01, 0, 0, 0);
        acc10 = __builtin_amdgcn_mfma_f32_16x16x32_bf16(af1, bf0, acc10, 0, 0, 0);
        acc11 = __builtin_amdgcn_mfma_f32_16x16x32_bf16(af1, bf1, acc11, 0, 0, 0);
    }

    floatx4 accs[2][2] = {{acc00, acc01}, {acc10, acc11}};
    const float scale = 0.35355339059327373f;
    const int rbase = m0 + wr * 32 + quad * 4;
    const int cbase = n0 + wc * 32 + l16;
    if (is_pq) {
#pragma unroll
        for (int r = 0; r < 2; ++r) {
#pragma unroll
            for (int reg = 0; reg < 4; ++reg) {
                const int gr = rbase + r * 16 + reg;
                if (gr >= NTOK) continue;
                const float nr = nrm_s[gr - m0];
#pragma unroll
                for (int c = 0; c < 2; ++c) {
                    const int gn = cbase + c * 16;
                    pq_out[((size_t)bh * NTOK + gr) * 256 + gn] =
                        f2bf(__expf(accs[r][c][reg] - nr) * scale);
                }
            }
        }
    } else {
#pragma unroll
        for (int r = 0; r < 2; ++r) {
#pragma unroll
            for (int reg = 0; reg < 4; ++reg) {
                const int gm = rbase + r * 16 + reg;   // f row
#pragma unroll
                for (int c = 0; c < 2; ++c) {
                    const int gn = cbase + c * 16;     // n col
                    float v = 0.f;
                    if (gn < NTOK)
                        v = __expf(accs[r][c][reg] - nrm_s[gn - n0]) * scale;
                    pkT[((size_t)bh * 256 + gm) * 256 + gn] = f2bf(v);
                }
            }
        }
    }
}

// ---------------- KVT[d][f] = sum_n vT[d][n]*pkT[f][n] + fused ksum[f] ----------------
__global__ __launch_bounds__(256) void kv_mfma(
    const u16* __restrict__ vT, const u16* __restrict__ pkT,
    u16* __restrict__ kvT, float* __restrict__ ksum)
{
    __shared__ u16 As[64][72];
    __shared__ u16 Bs[64][72];
    const int tid = threadIdx.x;
    const int lane = tid & 63, wave = tid >> 6;
    const int wr = wave & 1, wc = wave >> 1;
    const int l16 = lane & 15, quad = lane >> 4;
    const int bh = blockIdx.y;
    const int n0 = blockIdx.x * 64;
    const int srow = tid >> 2, skof = (tid & 3) * 16;

    floatx4 acc00 = {0.f,0.f,0.f,0.f}, acc01 = {0.f,0.f,0.f,0.f};
    floatx4 acc10 = {0.f,0.f,0.f,0.f}, acc11 = {0.f,0.f,0.f,0.f};
    float ksp = 0.f;

    const u16* ap = vT  + ((size_t)bh * 64 + srow) * 256 + skof;
    const u16* bp = pkT + ((size_t)bh * 256 + n0 + srow) * 256 + skof;

    for (int k0 = 0; k0 < 256; k0 += 64) {
        const uint4 a0 = *(const uint4*)(ap + k0);
        const uint4 a1 = *(const uint4*)(ap + k0 + 8);
        const uint4 b0 = *(const uint4*)(bp + k0);
        const uint4 b1 = *(const uint4*)(bp + k0 + 8);
        ksp += sum8bf(b0) + sum8bf(b1);
        if (k0) __syncthreads();
        *(uint4*)&As[srow][skof]     = a0;
        *(uint4*)&As[srow][skof + 8] = a1;
        *(uint4*)&Bs[srow][skof]     = b0;
        *(uint4*)&Bs[srow][skof + 8] = b1;
        __syncthreads();
#pragma unroll
        for (int ks = 0; ks < 2; ++ks) {
            const short8 af0 = *(const short8*)&As[wr*32 + l16][ks*32 + quad*8];
            const short8 af1 = *(const short8*)&As[wr*32 + 16 + l16][ks*32 + quad*8];
            const short8 bf0 = *(const short8*)&Bs[wc*32 + l16][ks*32 + quad*8];
            const short8 bf1 = *(const short8*)&Bs[wc*32 + 16 + l16][ks*32 + quad*8];
            acc00 = __builtin_amdgcn_mfma_f32_16x16x32_bf16(af0, bf0, acc00, 0, 0, 0);
            acc01 = __builtin_amdgcn_mfma_f32_16x16x32_bf16(af0, bf1, acc01, 0, 0, 0);
            acc10 = __builtin_amdgcn_mfma_f32_16x16x32_bf16(af1, bf0, acc10, 0, 0, 0);
            acc11 = __builtin_amdgcn_mfma_f32_16x16x32_bf16(af1, bf1, acc11, 0, 0, 0);
        }
    }

    ksp += __shfl_xor(ksp, 1);
    ksp += __shfl_xor(ksp, 2);
    if ((tid & 3) == 0) ksum[bh * 256 + n0 + srow] = ksp;

    floatx4 accs[2][2] = {{acc00, acc01}, {acc10, acc11}};
    const int rbase = wr * 32 + quad * 4;          // d row (<64)
    const int cbase = n0 + wc * 32 + l16;          // f col
#pragma unroll
    for (int r = 0; r < 2; ++r) {
#pragma unroll
        for (int reg = 0; reg < 4; ++reg) {
            const int gm = rbase + r * 16 + reg;
#pragma unroll
            for (int c = 0; c < 2; ++c) {
                const int gn = cbase + c * 16;
                kvT[((size_t)bh * 64 + gm) * 256 + gn] = f2bf(accs[r][c][reg]);
            }
        }
    }
}

// ---------------- attn: out[n][d] = (pq[n].KVT[d]) * dinv[n], dinv fused ----------------
__global__ __launch_bounds__(256) void attn_mfma(
    const u16* __restrict__ pq, const u16* __restrict__ kvT,
    const float* __restrict__ ksum, u16* __restrict__ attn_o)
{
    __shared__ u16 As[64][72];
    __shared__ u16 Bs[64][72];
    __shared__ float dinv_s[64];
    const int tid = threadIdx.x;
    const int lane = tid & 63, wave = tid >> 6;
    const int wr = wave & 1, wc = wave >> 1;
    const int l16 = lane & 15, quad = lane >> 4;
    const int bh = blockIdx.y, b = bh / NH, h = bh % NH;
    const int m0 = blockIdx.x * 64;
    const int srow = tid >> 2, skof = (tid & 3) * 16;

    floatx4 acc00 = {0.f,0.f,0.f,0.f}, acc01 = {0.f,0.f,0.f,0.f};
    floatx4 acc10 = {0.f,0.f,0.f,0.f}, acc11 = {0.f,0.f,0.f,0.f};
    float den = 0.f;

    const int gmA = m0 + srow;
    const bool mok = (gmA < NTOK);
    const u16* ap = pq  + ((size_t)bh * NTOK + gmA) * 256 + skof;
    const u16* bp = kvT + ((size_t)bh * 64 + srow) * 256 + skof;
    const float* ks = ksum + bh * 256 + skof;

    for (int k0 = 0; k0 < 256; k0 += 64) {
        uint4 a0 = {0,0,0,0}, a1 = {0,0,0,0};
        if (mok) {
            a0 = *(const uint4*)(ap + k0);
            a1 = *(const uint4*)(ap + k0 + 8);
            den += dot8bf(a0, ks + k0) + dot8bf(a1, ks + k0 + 8);
        }
        const uint4 b0 = *(const uint4*)(bp + k0);
        const uint4 b1 = *(const uint4*)(bp + k0 + 8);
        if (k0) __syncthreads();
        *(uint4*)&As[srow][skof]     = a0;
        *(uint4*)&As[srow][skof + 8] = a1;
        *(uint4*)&Bs[srow][skof]     = b0;
        *(uint4*)&Bs[srow][skof + 8] = b1;
        __syncthreads();
#pragma unroll
        for (int ks2 = 0; ks2 < 2; ++ks2) {
            const short8 af0 = *(const short8*)&As[wr*32 + l16][ks2*32 + quad*8];
            const short8 af1 = *(const short8*)&As[wr*32 + 16 + l16][ks2*32 + quad*8];
            const short8 bf0 = *(const short8*)&Bs[wc*32 + l16][ks2*32 + quad*8];
            const short8 bf1 = *(const short8*)&Bs[wc*32 + 16 + l16][ks2*32 + quad*8];
            acc00 = __builtin_amdgcn_mfma_f32_16x16x32_bf16(af0, bf0, acc00, 0, 0, 0);
            acc01 = __builtin_amdgcn_mfma_f32_16x16x32_bf16(af0, bf1, acc01, 0, 0, 0);
            acc10 = __builtin_amdgcn_mfma_f32_16x16x32_bf16(af1, bf0, acc10, 0, 0, 0);
            acc11 = __builtin_amdgcn_mfma_f32_16x16x32_bf16(af1, bf1, acc11, 0, 0, 0);
        }
    }

    den += __shfl_xor(den, 1);
    den += __shfl_xor(den, 2);
    if ((tid & 3) == 0) dinv_s[srow] = 1.f / den;
    __syncthreads();

    floatx4 accs[2][2] = {{acc00, acc01}, {acc10, acc11}};
    const int rbase = m0 + wr * 32 + quad * 4;     // n row
    const int cbase = wc * 32 + l16;               // d col (<64)
#pragma unroll
    for (int r = 0; r < 2; ++r) {
#pragma unroll
        for (int reg = 0; reg < 4; ++reg) {
            const int gm = rbase + r * 16 + reg;
            if (gm >= NTOK) continue;
            const float di = dinv_s[gm - m0];
#pragma unroll
            for (int c = 0; c < 2; ++c) {
                const int gn = cbase + c * 16;
                attn_o[((size_t)(b * NTOK + gm)) * EMB + h * 64 + gn] =
                    f2bf(accs[r][c][reg] * di);
            }
        }
    }
}

// ---------------- im2col (bf16 out) ----------------
__global__ void im2col_kernel(const float* __restrict__ x, u16* __restrict__ p, int total)
{
    const int i = blockIdx.x * 256 + threadIdx.x;
    if (i >= total) return;
    const int col = i % 768, row = i / 768;
    const int px = col & 15, py = (col >> 4) & 15, c = col >> 8;
    const int gx = row % 14, gy = (row / 14) % 14, b = row / 196;
    p[i] = f2bf(x[((size_t)(b * 3 + c) * 224 + gy * 16 + py) * 224 + gx * 16 + px]);
}

// ---------------- patch-embed finish ----------------
__global__ void embed_finish(const float* __restrict__ tok, const float* __restrict__ cls,
                             const float* __restrict__ pos, const float* __restrict__ w,
                             const float* __restrict__ b, float* __restrict__ h)
{
    const int wid = threadIdx.x >> 6, lane = threadIdx.x & 63;
    const int r = blockIdx.x * 4 + wid;
    if (r >= MTOT) return;
    const int bb = r / NTOK, t = r % NTOK;
    float* q = h + (size_t)r * EMB;
    if (t == 0) {
        q[lane]       = cls[lane]       + pos[lane];
        q[lane + 64]  = cls[lane + 64]  + pos[lane + 64];
        q[lane + 128] = cls[lane + 128] + pos[lane + 128];
        return;
    }
    const float* p = tok + ((size_t)bb * NPATCH + (t - 1)) * EMB;
    float x0 = p[lane], x1 = p[lane + 64], x2 = p[lane + 128];
    float s = x0 + x1 + x2;
#pragma unroll
    for (int off = 32; off; off >>= 1) s += __shfl_xor(s, off);
    const float mu = s * (1.f / 192.f);
    const float d0 = x0 - mu, d1 = x1 - mu, d2 = x2 - mu;
    float v = d0 * d0 + d1 * d1 + d2 * d2;
#pragma unroll
    for (int off = 32; off; off >>= 1) v += __shfl_xor(v, off);
    const float rstd = rsqrtf(v * (1.f / 192.f) + 1e-5f);
    const float* pr = pos + (size_t)t * EMB;
    q[lane]       = d0 * rstd * w[lane]       + b[lane]       + pr[lane];
    q[lane + 64]  = d1 * rstd * w[lane + 64]  + b[lane + 64]  + pr[lane + 64];
    q[lane + 128] = d2 * rstd * w[lane + 128] + b[lane + 128] + pr[lane + 128];
}

// ---------------- LayerNorm over 192; bf16 or fp32 out ----------------
__global__ void ln192(const float* __restrict__ in, int in_stride,
                      const float* __restrict__ w, const float* __restrict__ b,
                      u16* __restrict__ outb, float* __restrict__ outf, int rows)
{
    const int wid = threadIdx.x >> 6, lane = threadIdx.x & 63;
    const int r = blockIdx.x * 4 + wid;
    if (r >= rows) return;
    const float* p = in + (size_t)r * in_stride;
    float x0 = p[lane], x1 = p[lane + 64], x2 = p[lane + 128];
    float s = x0 + x1 + x2;
#pragma unroll
    for (int off = 32; off; off >>= 1) s += __shfl_xor(s, off);
    const float mu = s * (1.f / 192.f);
    const float d0 = x0 - mu, d1 = x1 - mu, d2 = x2 - mu;
    float v = d0 * d0 + d1 * d1 + d2 * d2;
#pragma unroll
    for (int off = 32; off; off >>= 1) v += __shfl_xor(v, off);
    const float rstd = rsqrtf(v * (1.f / 192.f) + 1e-5f);
    const float y0 = d0 * rstd * w[lane]       + b[lane];
    const float y1 = d1 * rstd * w[lane + 64]  + b[lane + 64];
    const float y2 = d2 * rstd * w[lane + 128] + b[lane + 128];
    if (outf) {
        float* q = outf + (size_t)r * EMB;
        q[lane] = y0; q[lane + 64] = y1; q[lane + 128] = y2;
    } else {
        u16* q = outb + (size_t)r * EMB;
        q[lane] = f2bf(y0); q[lane + 64] = f2bf(y1); q[lane + 128] = f2bf(y2);
    }
}

// ---------------- fp32 GEMM (head / exits only) ----------------
__global__ __launch_bounds__(256) void gemm_f32(
    const float* __restrict__ A, const float* __restrict__ Bm,
    const float* __restrict__ bias, float* __restrict__ C,
    int M, int N, int K)
{
    __shared__ float As[16][68];
    __shared__ float Bs[16][64];
    const int tid = threadIdx.x;
    const int tx = tid & 15, ty = tid >> 4;
    const int m0 = blockIdx.y * 64, n0 = blockIdx.x * 64;
    float acc[4][4] = {};

    for (int k0 = 0; k0 < K; k0 += 16) {
        {
            const int c = tid & 15, r4 = tid >> 4;
#pragma unroll
            for (int i = 0; i < 4; ++i) {
                const int r = r4 + i * 16, gm = m0 + r;
                As[c][r] = (gm < M) ? A[(size_t)gm * K + (k0 + c)] : 0.f;
            }
        }
        {
            const int cb = tid & 63, rb4 = tid >> 6;
#pragma unroll
            for (int i = 0; i < 4; ++i) {
                const int rb = rb4 + i * 4;
                const int gn = n0 + cb;
                Bs[rb][cb] = (gn < N) ? Bm[(size_t)(k0 + rb) * N + gn] : 0.f;
            }
        }
        __syncthreads();
#pragma unroll
        for (int kk = 0; kk < 16; ++kk) {
            const float4 av = *reinterpret_cast<const float4*>(&As[kk][ty * 4]);
            const float4 bv = *reinterpret_cast<const float4*>(&Bs[kk][tx * 4]);
            const float a_[4] = {av.x, av.y, av.z, av.w};
            const float b_[4] = {bv.x, bv.y, bv.z, bv.w};
#pragma unroll
            for (int i2 = 0; i2 < 4; ++i2)
#pragma unroll
                for (int j2 = 0; j2 < 4; ++j2)
                    acc[i2][j2] = fmaf(a_[i2], b_[j2], acc[i2][j2]);
        }
        __syncthreads();
    }

#pragma unroll
    for (int i = 0; i < 4; ++i) {
        const int gm = m0 + ty * 4 + i;
        if (gm >= M) continue;
#pragma unroll
        for (int j = 0; j < 4; ++j) {
            const int gn = n0 + tx * 4 + j;
            if (gn >= N) continue;
            C[(size_t)gm * N + gn] = acc[i][j] + bias[gn];
        }
    }
}

// ---------------- mean over tokens for exits ----------------
__global__ void pool_kernel(const float* __restrict__ h, float* __restrict__ pooled)
{
    const int b = blockIdx.x, e = threadIdx.x;  // block 192
    float s = 0.f;
    for (int n = 0; n < NTOK; ++n) s += h[((size_t)(b * NTOK + n)) * EMB + e];
    pooled[b * EMB + e] = s * (1.f / 197.f);
}

// ---------------- host launch ----------------
extern "C" void kernel_launch(void* const* d_in, const int* in_sizes, int n_in,
                              void* d_out, int out_size, void* d_ws, size_t ws_size,
                              hipStream_t stream)
{
    const float* x          = (const float*)d_in[0];
    const float* patch_w    = (const float*)d_in[1];
    const float* patch_b    = (const float*)d_in[2];
    const float* pe_norm_w  = (const float*)d_in[3];
    const float* pe_norm_b  = (const float*)d_in[4];
    const float* cls_token  = (const float*)d_in[5];
    const float* pos_embed  = (const float*)d_in[6];
    const float* norm1_w    = (const float*)d_in[7];
    const float* norm1_b    = (const float*)d_in[8];
    const float* qkv_w      = (const float*)d_in[9];
    const float* qkv_b      = (const float*)d_in[10];
    const float* proj_mat   = (const float*)d_in[11];
    const float* attn_pw    = (const float*)d_in[12];
    const float* attn_pb    = (const float*)d_in[13];
    const float* norm2_w    = (const float*)d_in[14];
    const float* norm2_b    = (const float*)d_in[15];
    const float* fc1_w      = (const float*)d_in[16];
    const float* fc1_b      = (const float*)d_in[17];
    const float* fc2_w      = (const float*)d_in[18];
    const float* fc2_b      = (const float*)d_in[19];
    const float* exit_w     = (const float*)d_in[20];
    const float* exit_b     = (const float*)d_in[21];
    const float* fnorm_w    = (const float*)d_in[22];
    const float* fnorm_b    = (const float*)d_in[23];
    const float* head_w     = (const float*)d_in[24];
    const float* head_b     = (const float*)d_in[25];
    float* out = (float*)d_out;

    float* ws = (float*)d_ws;
    // workspace layout (float-slot offsets)
    float* H     = ws + 0;                  // 12608*192 fp32       -> 2,420,736
    u16*   QKVB  = (u16*)(ws + 2420736);    // 12608*576 bf16 (3,631,104 fl)
    u16*   XLNB  = (u16*)(ws + 6051840);    // 12608*192 bf16 (1,210,368 fl)
    u16*   PQb   = (u16*)(ws + 7262208);    // 192*197*256 bf16 (4,841,472 fl)
    u16*   PKT   = (u16*)(ws + 12103680);   // 192*256*256 bf16 (6,291,456 fl)
    u16*   VT    = (u16*)(ws + 18395136);   // 192*64*256 bf16 (1,572,864 fl)
    u16*   KVT   = (u16*)(ws + 19968000);   // 192*64*256 bf16 (1,572,864 fl)
    u16*   MIDB  = (u16*)(ws + 21540864);   // 12608*768 bf16 (4,841,472 fl)
    u16*   ATNB  = (u16*)(ws + 26382336);   // 12608*192 bf16 (1,210,368 fl)
    float* XLNF  = ws + 27592704;           // 64*192
    float* POOL  = ws + 27604992;           // 64*192
    float* KSUM  = ws + 27617280;           // 192*256
    u16*   QKVWT = (u16*)(ws + 27666432);   // 12*576*192 bf16 (663,552 fl)
    u16*   APWT  = (u16*)(ws + 28329984);   // 12*192*192 bf16 (221,184 fl)
    u16*   F1WT  = (u16*)(ws + 28551168);   // 12*768*192 bf16 (884,736 fl)
    u16*   F2WT  = (u16*)(ws + 29435904);   // 12*192*768 bf16 (884,736 fl)
    u16*   PATWB = (u16*)(ws + 30320640);   // 192*768 bf16 (73,728 fl)
    u16*   PMB   = (u16*)(ws + 30394368);   // 12*256*64 bf16 (98,304 fl)
    // aliases (disjoint lifetimes)
    u16*   P_IMB = MIDB;                    // im2col [12544,768] bf16 (prologue only)
    float* TOK   = (float*)QKVB;            // patch tokens [12544,192] fp32 (prologue only)

    if (ws_size < (size_t)30492672 * sizeof(float)) return;

    // ---- weight prep ----
    cvt_bf16<<<(147456 + 255) / 256, 256, 0, stream>>>(patch_w, PATWB, 147456);
    cvt_bf16<<<(196608 + 255) / 256, 256, 0, stream>>>(proj_mat, PMB, 196608);
    tr_bf16<<<(1327104 + 255) / 256, 256, 0, stream>>>(qkv_w,   QKVWT, 192, 576, 1327104);
    tr_bf16<<<(442368 + 255) / 256, 256, 0, stream>>>(attn_pw, APWT,  192, 192, 442368);
    tr_bf16<<<(1769472 + 255) / 256, 256, 0, stream>>>(fc1_w,   F1WT,  192, 768, 1769472);
    tr_bf16<<<(1769472 + 255) / 256, 256, 0, stream>>>(fc2_w,   F2WT,  768, 192, 1769472);

    // ---- patch embed ----
    im2col_kernel<<<(MPAT * 768 + 255) / 256, 256, 0, stream>>>(x, P_IMB, MPAT * 768);
    gemm_bf16<<<dim3(3, 196), 256, 0, stream>>>(P_IMB, PATWB, patch_b, nullptr,
                                                TOK, nullptr, MPAT, EMB, 768, 0);
    embed_finish<<<(MTOT + 3) / 4, 256, 0, stream>>>(TOK, cls_token, pos_embed,
                                                     pe_norm_w, pe_norm_b, H);
    // LN1 of layer 0
    ln192<<<(MTOT + 3) / 4, 256, 0, stream>>>(H, EMB, norm1_w, norm1_b,
                                              XLNB, nullptr, MTOT);

    // ---- transformer layers ----
    for (int i = 0; i < 12; ++i) {
        const u16* qwt  = QKVWT + (size_t)i * 576 * 192;
        const u16* pwt  = APWT  + (size_t)i * 192 * 192;
        const u16* f1wt = F1WT  + (size_t)i * 768 * 192;
        const u16* f2wt = F2WT  + (size_t)i * 192 * 768;
        const u16* pmb  = PMB   + (size_t)i * 256 * 64;
        const float* qb  = qkv_b   + (size_t)i * 576;
        const float* pb  = attn_pb + (size_t)i * 192;
        const float* f1b = fc1_b   + (size_t)i * 768;
        const float* f2b = fc2_b   + (size_t)i * 192;

        gemm_bf16<<<dim3(9, 197), 256, 0, stream>>>(XLNB, qwt, qb, nullptr,
                                                    nullptr, QKVB, MTOT, 576, 192, 3);
        attn_prep<<<dim3(36, BHT), 256, 0, stream>>>(QKVB, pmb, PQb, PKT, VT);
        kv_mfma<<<dim3(4, BHT), 256, 0, stream>>>(VT, PKT, KVT, KSUM);
        attn_mfma<<<dim3(4, BHT), 256, 0, stream>>>(PQb, KVT, KSUM, ATNB);
        gemm_bf16<<<dim3(3, 197), 256, 0, stream>>>(ATNB, pwt, pb, H,
                                                    H, nullptr, MTOT, EMB, EMB, 1);
        ln192<<<(MTOT + 3) / 4, 256, 0, stream>>>(H, EMB, norm2_w + i * EMB,
                                                  norm2_b + i * EMB, XLNB, nullptr, MTOT);
        gemm_bf16<<<dim3(12, 197), 256, 0, stream>>>(XLNB, f1wt, f1b, nullptr,
                                                     nullptr, MIDB, MTOT, MLPD, 192, 2);
        gemm_bf16<<<dim3(3, 197), 256, 0, stream>>>(MIDB, f2wt, f2b, H,
                                                    H, nullptr, MTOT, EMB, MLPD, 1);

        const int e = (i == 3) ? 0 : (i == 7) ? 1 : (i == 11) ? 2 : -1;
        if (e >= 0) {
            pool_kernel<<<BB, 192, 0, stream>>>(H, POOL);
            gemm_f32<<<dim3(16, 1), 256, 0, stream>>>(POOL, exit_w + (size_t)e * 192 * 1000,
                                                      exit_b + (size_t)e * 1000,
                                                      out + (size_t)(1 + e) * BB * NCLS,
                                                      BB, NCLS, EMB);
        }
        if (i < 11) {
            ln192<<<(MTOT + 3) / 4, 256, 0, stream>>>(H, EMB, norm1_w + (i + 1) * EMB,
                                                      norm1_b + (i + 1) * EMB,
                                                      XLNB, nullptr, MTOT);
        }
    }

    // ---- head ----
    ln192<<<(BB + 3) / 4, 256, 0, stream>>>(H, NTOK * EMB, fnorm_w, fnorm_b,
                                            nullptr, XLNF, BB);
    gemm_f32<<<dim3(16, 1), 256, 0, stream>>>(XLNF, head_w, head_b, out, BB, NCLS, EMB);
}